// Round 5
// baseline (291.860 us; speedup 1.0000x reference)
//
#include <hip/hip_runtime.h>

// PartialMatchingLoss: mean over (b,m) of min_n ||partial[b,m] - completed[b,n]||
// B=8, M=4096 (partial), N=8192 (completed), D=3, fp32.
//
// R10: EXACT pruned NN search (brute force falsified as a local minimum:
// R2 TLP / R8 SMEM / R9 ILP-ratio all neutral-negative; main stuck ~3x its
// VALU floor). Counting-sort completed AND queries by x into 256 bins per
// batch; each query scans its bin then expands l/r, stopping when the bin-edge
// x-gap^2 >= current d^2 (exact: bin edges lower-bound |x_c - x_q|, clamping
// only moves points inward so bounds stay valid). ~12x fewer pairs.
// 4 lanes split each query's candidates (stride-4, coalesced); pruning uses
// the quad-shared min (shfl_xor 1,2) making quad control flow lockstep.
// Per-pair math identical to the passing kernel: f = 0.5||c||^2 - p.c via
// 3-FMA chain; d = sqrt(max(2f + ||p||^2, 0)).

constexpr int B  = 8;
constexpr int N  = 8192;
constexpr int M  = 4096;
constexpr int NB = 256;                       // x-bins per batch
constexpr float XLO = -6.0f, XHI = 6.0f;      // N(0,1): no sample near +/-6
constexpr float BINW = (XHI - XLO) / NB;      // 0.046875
constexpr float BINV = (float)NB / (XHI - XLO);
constexpr int ROWS = B * M;                   // 32768
constexpr float FMAX = 3.402823466e38f;

// ws layout:
//   [0, 8*257*4)        cStart[8][257] (int)
//   [16K, 16K+512K)     cPk float4[8][8192]  (x,y,z,0.5||c||^2), x-bin-sorted
//   [16K+512K, +256K)   qPk float4[8][4096]  (x,y,z,||p||^2),    x-bin-sorted
constexpr size_t OFF_CPK = 16 * 1024;
constexpr size_t OFF_QPK = OFF_CPK + (size_t)B * N * 16;

__device__ __forceinline__ int binOf(float x) {
    int k = (int)floorf((x - XLO) * BINV);
    return k < 0 ? 0 : (k > NB - 1 ? NB - 1 : k);
}

// ---- prep: per (batch, set) block -> LDS histogram, scan, scatter ----------
__global__ __launch_bounds__(256) void pml_prep(const float* __restrict__ completed,
                                                const float* __restrict__ partial,
                                                int* __restrict__ cStart,
                                                float4* __restrict__ cPk,
                                                float4* __restrict__ qPk,
                                                float* __restrict__ out) {
    __shared__ int cnt[NB];
    __shared__ int st[NB + 1];
    const int t    = threadIdx.x;
    const int role = blockIdx.x;              // 0..15
    const int b    = role >> 1;
    const bool isQ = role & 1;
    const int n    = isQ ? M : N;
    const float* src = isQ ? partial + (size_t)b * M * 3
                           : completed + (size_t)b * N * 3;

    for (int k = t; k < NB; k += 256) cnt[k] = 0;
    __syncthreads();
    for (int i = t; i < n; i += 256)
        atomicAdd(&cnt[binOf(src[3 * i])], 1);
    __syncthreads();
    if (t == 0) {
        int acc = 0;
        for (int k = 0; k < NB; ++k) { st[k] = acc; acc += cnt[k]; }
        st[NB] = acc;
    }
    __syncthreads();
    if (!isQ)
        for (int k = t; k <= NB; k += 256) cStart[b * (NB + 1) + k] = st[k];
    for (int k = t; k < NB; k += 256) cnt[k] = 0;     // reuse as cursors
    __syncthreads();
    for (int i = t; i < n; i += 256) {
        float x = src[3 * i], y = src[3 * i + 1], z = src[3 * i + 2];
        int k = binOf(x);
        int pos = st[k] + atomicAdd(&cnt[k], 1);
        if (isQ) qPk[(size_t)b * M + pos] = make_float4(x, y, z, x * x + y * y + z * z);
        else     cPk[(size_t)b * N + pos] = make_float4(x, y, z, 0.5f * (x * x + y * y + z * z));
    }
    if (role == 0 && t == 0) out[0] = 0.0f;   // main runs strictly after
}

// ---- main: 4 lanes per query, expanding-bin exact NN -----------------------
constexpr int SPLIT = 4;
constexpr int MT = 256;
constexpr int MAIN_BLOCKS = ROWS * SPLIT / MT;   // 512

__global__ __launch_bounds__(MT) void pml_main(const int* __restrict__ cStart,
                                               const float4* __restrict__ cPk,
                                               const float4* __restrict__ qPk,
                                               float* __restrict__ out) {
    const int g   = blockIdx.x * MT + threadIdx.x;
    const int sub = g & (SPLIT - 1);
    const int q   = g >> 2;                   // sorted row id
    const int b   = q >> 12;                  // / M
    const int qi  = q & (M - 1);

    const float4 Q = qPk[(size_t)b * M + qi]; // quad-broadcast load
    const float px = -Q.x, py = -Q.y, pz = -Q.z, psq = Q.w;
    const int ib = binOf(Q.x);
    const int* bs = cStart + b * (NB + 1);
    const float4* cb = cPk + (size_t)b * N;

    float best = FMAX;                        // best f = 0.5||c||^2 - p.c
    {   // own bin
        const int e = bs[ib + 1];
        for (int i = bs[ib] + sub; i < e; i += SPLIT) {
            float4 c = cb[i];
            float f = fmaf(px, c.x, fmaf(py, c.y, fmaf(pz, c.z, c.w)));
            best = fminf(best, f);
        }
    }
    int l = ib - 1, r = ib + 1;
    bool dL = (l < 0), dR = (r >= NB);
    while (!(dL && dR)) {
        // quad-shared min: identical across the 4 lanes -> lockstep control
        float bs4 = fminf(best, __shfl_xor(best, 1));
        bs4 = fminf(bs4, __shfl_xor(bs4, 2));
        const float d2 = fmaxf(fmaf(2.0f, bs4, psq), 0.0f);
        if (!dR) {
            float gap = fmaf((float)r, BINW, XLO) - Q.x;    // binLeft(r) - x >= 0
            if (gap * gap >= d2) dR = true;
            else {
                const int e = bs[r + 1];
                for (int i = bs[r] + sub; i < e; i += SPLIT) {
                    float4 c = cb[i];
                    float f = fmaf(px, c.x, fmaf(py, c.y, fmaf(pz, c.z, c.w)));
                    best = fminf(best, f);
                }
                if (++r >= NB) dR = true;
            }
        }
        if (!dL) {
            float gap = Q.x - fmaf((float)(l + 1), BINW, XLO); // x - binRight(l) >= 0
            if (gap * gap >= d2) dL = true;
            else {
                const int e = bs[l + 1];
                for (int i = bs[l] + sub; i < e; i += SPLIT) {
                    float4 c = cb[i];
                    float f = fmaf(px, c.x, fmaf(py, c.y, fmaf(pz, c.z, c.w)));
                    best = fminf(best, f);
                }
                if (--l < 0) dL = true;
            }
        }
    }
    best = fminf(best, __shfl_xor(best, 1));
    best = fminf(best, __shfl_xor(best, 2));
    float s = (sub == 0) ? sqrtf(fmaxf(fmaf(2.0f, best, psq), 0.0f)) : 0.0f;

#pragma unroll
    for (int off = 32; off > 0; off >>= 1) s += __shfl_down(s, off);
    __shared__ float red[MT / 64];
    const int lane = threadIdx.x & 63, wid = threadIdx.x >> 6;
    if (lane == 0) red[wid] = s;
    __syncthreads();
    if (threadIdx.x == 0)
        atomicAdd(out, (red[0] + red[1] + red[2] + red[3]) * (1.0f / (float)ROWS));
}

extern "C" void kernel_launch(void* const* d_in, const int* in_sizes, int n_in,
                              void* d_out, int out_size, void* d_ws, size_t ws_size,
                              hipStream_t stream) {
    const float* completed = (const float*)d_in[0];  // (8, 8192, 3)
    const float* partial   = (const float*)d_in[1];  // (8, 4096, 3)
    float* out = (float*)d_out;
    char*  ws  = (char*)d_ws;

    int*    cStart = (int*)ws;
    float4* cPk    = (float4*)(ws + OFF_CPK);
    float4* qPk    = (float4*)(ws + OFF_QPK);

    pml_prep<<<2 * B, 256, 0, stream>>>(completed, partial, cStart, cPk, qPk, out);
    pml_main<<<MAIN_BLOCKS, MT, 0, stream>>>(cStart, cPk, qPk, out);
}

// Round 6
// 179.025 us; speedup vs baseline: 1.6303x; 1.6303x over previous
//
#include <hip/hip_runtime.h>

// PartialMatchingLoss: mean over (b,m) of min_n ||partial[b,m] - completed[b,n]||
// B=8, M=4096 (partial), N=8192 (completed), D=3, fp32.
//
// R11: dense two-phase pruned NN. R10 proved the pruned candidate set is
// exact (passed, absmax 0, FETCH 4.2MB) but its per-query expanding loop ran
// at 9% VALUBusy (divergence/latency). Now: queries x-sorted; 32 consecutive
// sorted queries per block share one candidate window -> flat uniform scans.
// Phase 1: scan spanned bins +-1 -> d_ub per query. Phase 2: one jump to
// binOf(xL - max d_ub) .. binOf(xR + max d_ub), scan the delta. Exact:
// for any query q, gap(q, unscanned) >= md >= d_ub(q) >= d_final(q).
// Per-pair math identical: f = 0.5||c||^2 - p.c (3-FMA), d = sqrt(2f+||p||^2).

constexpr int B  = 8;
constexpr int N  = 8192;
constexpr int M  = 4096;
constexpr int NB = 256;                       // x-bins per batch
constexpr float XLO = -6.0f, XHI = 6.0f;      // N(0,1): no sample near +/-6
constexpr float BINW = (XHI - XLO) / NB;
constexpr float BINV = (float)NB / (XHI - XLO);
constexpr int ROWS = B * M;                   // 32768
constexpr float FMAX = 3.402823466e38f;

constexpr size_t OFF_CPK = 16 * 1024;
constexpr size_t OFF_QPK = OFF_CPK + (size_t)B * N * 16;

__device__ __forceinline__ int binOf(float x) {
    int k = (int)floorf((x - XLO) * BINV);
    return k < 0 ? 0 : (k > NB - 1 ? NB - 1 : k);
}

// ---- prep: per (batch, set) block -> LDS histogram, parallel scan, scatter --
__global__ __launch_bounds__(256) void pml_prep(const float* __restrict__ completed,
                                                const float* __restrict__ partial,
                                                int* __restrict__ cStart,
                                                float4* __restrict__ cPk,
                                                float4* __restrict__ qPk,
                                                float* __restrict__ out) {
    __shared__ int cnt[NB];
    __shared__ int sc[NB];
    __shared__ int st[NB + 1];
    const int t    = threadIdx.x;
    const int role = blockIdx.x;              // 0..15
    const int b    = role >> 1;
    const bool isQ = role & 1;
    const int n    = isQ ? M : N;
    const float* src = isQ ? partial + (size_t)b * M * 3
                           : completed + (size_t)b * N * 3;

    cnt[t] = 0;
    __syncthreads();
    for (int i = t; i < n; i += 256)
        atomicAdd(&cnt[binOf(src[3 * i])], 1);
    __syncthreads();
    // Hillis-Steele inclusive scan (NB == 256 == NT)
    sc[t] = cnt[t];
    __syncthreads();
#pragma unroll
    for (int o = 1; o < NB; o <<= 1) {
        int v = sc[t];
        if (t >= o) v += sc[t - o];
        __syncthreads();
        sc[t] = v;
        __syncthreads();
    }
    st[t + 1] = sc[t];
    if (t == 0) st[0] = 0;
    __syncthreads();
    if (!isQ)
        for (int k = t; k <= NB; k += 256) cStart[b * (NB + 1) + k] = st[k];
    cnt[t] = 0;                                // reuse as cursors
    __syncthreads();
    for (int i = t; i < n; i += 256) {
        float x = src[3 * i], y = src[3 * i + 1], z = src[3 * i + 2];
        int k = binOf(x);
        int pos = st[k] + atomicAdd(&cnt[k], 1);
        if (isQ) qPk[(size_t)b * M + pos] = make_float4(x, y, z, x * x + y * y + z * z);
        else     cPk[(size_t)b * N + pos] = make_float4(x, y, z, 0.5f * (x * x + y * y + z * z));
    }
    if (role == 0 && t == 0) out[0] = 0.0f;   // main runs strictly after
}

// ---- main: 32 sorted queries/block, 8 lanes/query, dense two-phase scan ----
constexpr int QPB   = 32;                     // queries per block
constexpr int SPLIT = 8;                      // lanes per query
constexpr int NT2   = QPB * SPLIT;            // 256
constexpr int MAIN_BLOCKS = ROWS / QPB;       // 1024
constexpr int BPB = MAIN_BLOCKS / B;          // 128 blocks per batch

__global__ __launch_bounds__(NT2) void pml_main(const int* __restrict__ cStart,
                                                const float4* __restrict__ cPk,
                                                const float4* __restrict__ qPk,
                                                float* __restrict__ out) {
    const int t   = threadIdx.x;
    const int sub = t & (SPLIT - 1);
    const int ql  = t >> 3;                   // 0..31
    const int blk = blockIdx.x;
    const int b   = blk / BPB;
    const int qbase = (blk % BPB) * QPB;

    const float4 Q = qPk[(size_t)b * M + qbase + ql];
    const float px = -Q.x, py = -Q.y, pz = -Q.z, psq = Q.w;
    const int* bs = cStart + b * (NB + 1);
    const float4* cb = cPk + (size_t)b * N;

    // Block x-extremes (within-bin order is arbitrary -> must reduce).
    float xmn = Q.x, xmx = Q.x;
#pragma unroll
    for (int o = 1; o < 64; o <<= 1) {
        xmn = fminf(xmn, __shfl_xor(xmn, o));
        xmx = fmaxf(xmx, __shfl_xor(xmx, o));
    }
    __shared__ float smn[4], smx[4];
    const int wid = t >> 6, lane = t & 63;
    if (lane == 0) { smn[wid] = xmn; smx[wid] = xmx; }
    __syncthreads();
    const float xL = fminf(fminf(smn[0], smn[1]), fminf(smn[2], smn[3]));
    const float xR = fmaxf(fmaxf(smx[0], smx[1]), fmaxf(smx[2], smx[3]));

    const int l0 = max(binOf(xL) - 1, 0);
    const int r0 = min(binOf(xR) + 1, NB - 1);
    const int lo = bs[l0], hi = bs[r0 + 1];

    // Phase 1: spanned bins +-1
    float best = FMAX;
    for (int i = lo + sub; i < hi; i += SPLIT) {
        float4 c = cb[i];
        best = fminf(best, fmaf(px, c.x, fmaf(py, c.y, fmaf(pz, c.z, c.w))));
    }

    // per-query d_ub^2, block max
    float bq = fminf(best, __shfl_xor(best, 1));
    bq = fminf(bq, __shfl_xor(bq, 2));
    bq = fminf(bq, __shfl_xor(bq, 4));
    float d2 = fmaxf(fmaf(2.0f, bq, psq), 0.0f);
    float mx = d2;
#pragma unroll
    for (int o = 1; o < 64; o <<= 1) mx = fmaxf(mx, __shfl_xor(mx, o));
    __syncthreads();                          // smx reuse
    if (lane == 0) smx[wid] = mx;
    __syncthreads();
    const float md = sqrtf(fmaxf(fmaxf(smx[0], smx[1]), fmaxf(smx[2], smx[3])));

    // Phase 2: one jump to the guaranteed-exact window, scan the delta.
    const int lT = binOf(xL - md);
    const int rT = binOf(xR + md);
    const int lo2 = bs[lT], hi2 = bs[rT + 1];
    for (int i = lo2 + sub; i < lo; i += SPLIT) {
        float4 c = cb[i];
        best = fminf(best, fmaf(px, c.x, fmaf(py, c.y, fmaf(pz, c.z, c.w))));
    }
    for (int i = hi + sub; i < hi2; i += SPLIT) {
        float4 c = cb[i];
        best = fminf(best, fmaf(px, c.x, fmaf(py, c.y, fmaf(pz, c.z, c.w))));
    }

    // merge 8 lanes, then block-sum of sqrt
    bq = fminf(best, __shfl_xor(best, 1));
    bq = fminf(bq, __shfl_xor(bq, 2));
    bq = fminf(bq, __shfl_xor(bq, 4));
    float s = (sub == 0) ? sqrtf(fmaxf(fmaf(2.0f, bq, psq), 0.0f)) : 0.0f;
#pragma unroll
    for (int off = 32; off > 0; off >>= 1) s += __shfl_down(s, off);
    __shared__ float red[4];
    if (lane == 0) red[wid] = s;
    __syncthreads();
    if (t == 0)
        atomicAdd(out, (red[0] + red[1] + red[2] + red[3]) * (1.0f / (float)ROWS));
}

extern "C" void kernel_launch(void* const* d_in, const int* in_sizes, int n_in,
                              void* d_out, int out_size, void* d_ws, size_t ws_size,
                              hipStream_t stream) {
    const float* completed = (const float*)d_in[0];  // (8, 8192, 3)
    const float* partial   = (const float*)d_in[1];  // (8, 4096, 3)
    float* out = (float*)d_out;
    char*  ws  = (char*)d_ws;

    int*    cStart = (int*)ws;
    float4* cPk    = (float4*)(ws + OFF_CPK);
    float4* qPk    = (float4*)(ws + OFF_QPK);

    pml_prep<<<2 * B, 256, 0, stream>>>(completed, partial, cStart, cPk, qPk, out);
    pml_main<<<MAIN_BLOCKS, NT2, 0, stream>>>(cStart, cPk, qPk, out);
}

// Round 7
// 146.937 us; speedup vs baseline: 1.9863x; 1.2184x over previous
//
#include <hip/hip_runtime.h>

// PartialMatchingLoss: mean over (b,m) of min_n ||partial[b,m] - completed[b,n]||
// B=8, M=4096 (partial), N=8192 (completed), D=3, fp32.
//
// R12: dense pruned NN, LDS-staged. R11 (block-shared window, global re-reads,
// strided loops) ran 111 us at 33% VALUBusy: 8x redundant loads + loop overhead.
// Now: 64 sorted queries/block (512 blocks), window staged ONCE into LDS in
// coalesced chunks, scanned by a uniform sentinel-padded loop (no tail
// divergence; 4 distinct 16B addrs per ds_read -> conflict-free broadcast).
// Two-phase exactness identical to R10/R11 (both passed, absmax 0.0):
//   phase 1: bins [binOf(xL)-1, binOf(xR)+1] -> per-query d_ub
//   phase 2: md = block max d_ub; extend to binOf(xL-md)..binOf(xR+md).
//   Any unscanned candidate c: |xc-xq| > md >= d_ub(q) >= d(q). Exact.
// Prep: 64 blocks (4 slices per (batch,set)); each block histograms ALL
// slices (redundant, cheap) -> local scatter bases, 4x parallel scatter.
// Per-pair math unchanged: f = 0.5||c||^2 - p.c (3 FMA), d = sqrt(2f+||p||^2).

constexpr int B  = 8;
constexpr int N  = 8192;
constexpr int M  = 4096;
constexpr int NB = 256;                       // x-bins per batch
constexpr float XLO = -6.0f, XHI = 6.0f;      // N(0,1): no sample near +/-6
constexpr float BINW = (XHI - XLO) / NB;      // 3/64, exact in binary
constexpr float BINV = (float)NB / (XHI - XLO);
constexpr int ROWS = B * M;                   // 32768
constexpr float FMAX = 3.402823466e38f;

// ws layout: cStart[8][257] ints | cPk float4[8][8192] | qPk float4[8][4096]
constexpr size_t OFF_CPK = 16 * 1024;
constexpr size_t OFF_QPK = OFF_CPK + (size_t)B * N * 16;

__device__ __forceinline__ int binOf(float x) {
    int k = (int)floorf((x - XLO) * BINV);    // v_cvt saturates on +/-inf
    return k < 0 ? 0 : (k > NB - 1 ? NB - 1 : k);
}

// ---- prep: 64 blocks = (batch,set) x 4 slices ------------------------------
constexpr int PT = 256;

__global__ __launch_bounds__(PT) void pml_prep(const float* __restrict__ completed,
                                               const float* __restrict__ partial,
                                               int* __restrict__ cStart,
                                               float4* __restrict__ cPk,
                                               float4* __restrict__ qPk,
                                               float* __restrict__ out) {
    __shared__ int cnt[4][NB];
    __shared__ int sc[NB];
    __shared__ int st[NB + 1];
    __shared__ int base[NB];
    __shared__ int cur[NB];

    const int t     = threadIdx.x;
    const int role  = blockIdx.x >> 2;        // 0..15 = (b, set)
    const int slice = blockIdx.x & 3;
    const int b     = role >> 1;
    const bool isQ  = role & 1;
    const int n     = isQ ? M : N;
    const int ngr   = n / 4;                  // 4-point groups (48B = 3 float4)
    const int sshift = isQ ? 8 : 9;           // group >> sshift = slice id
    const float* src = isQ ? partial + (size_t)b * M * 3
                           : completed + (size_t)b * N * 3;
    const float4* sv = (const float4*)src;

    for (int k = t; k < 4 * NB; k += PT) ((int*)cnt)[k] = 0;
    __syncthreads();

    // histogram of ALL slices (redundant across the 4 sibling blocks)
    for (int g = t; g < ngr; g += PT) {
        float4 a = sv[3*g], b4 = sv[3*g+1], c4 = sv[3*g+2];
        int s = g >> sshift;
        atomicAdd(&cnt[s][binOf(a.x)],  1);
        atomicAdd(&cnt[s][binOf(a.w)],  1);
        atomicAdd(&cnt[s][binOf(b4.z)], 1);
        atomicAdd(&cnt[s][binOf(c4.y)], 1);
    }
    __syncthreads();

    // inclusive scan of per-bin totals (Hillis-Steele, NB == PT)
    sc[t] = cnt[0][t] + cnt[1][t] + cnt[2][t] + cnt[3][t];
    __syncthreads();
#pragma unroll
    for (int o = 1; o < NB; o <<= 1) {
        int v = sc[t];
        if (t >= o) v += sc[t - o];
        __syncthreads();
        sc[t] = v;
        __syncthreads();
    }
    st[t + 1] = sc[t];
    if (t == 0) st[0] = 0;
    __syncthreads();

    if (!isQ && slice == 0)
        for (int k = t; k <= NB; k += PT) cStart[b * (NB + 1) + k] = st[k];

    // this slice's scatter base = bin start + earlier slices' counts
    {
        int v = st[t];
        if (slice > 0) v += cnt[0][t];
        if (slice > 1) v += cnt[1][t];
        if (slice > 2) v += cnt[2][t];
        base[t] = v;
        cur[t]  = 0;
    }
    __syncthreads();

    // scatter own slice only
    const int g0 = slice << sshift;
    const int g1 = g0 + (ngr >> 2);
    float4* dst = isQ ? qPk + (size_t)b * M : cPk + (size_t)b * N;
    for (int g = g0 + t; g < g1; g += PT) {
        float4 a = sv[3*g], b4 = sv[3*g+1], c4 = sv[3*g+2];
        float xs[4] = {a.x, a.w,  b4.z, c4.y};
        float ys[4] = {a.y, b4.x, b4.w, c4.z};
        float zs[4] = {a.z, b4.y, c4.x, c4.w};
#pragma unroll
        for (int u = 0; u < 4; ++u) {
            int k = binOf(xs[u]);
            int pos = base[k] + atomicAdd(&cur[k], 1);
            float q2 = xs[u]*xs[u] + ys[u]*ys[u] + zs[u]*zs[u];
            dst[pos] = make_float4(xs[u], ys[u], zs[u], isQ ? q2 : 0.5f * q2);
        }
    }
    if (blockIdx.x == 0 && t == 0) out[0] = 0.0f;   // main runs strictly after
}

// ---- main: 64 queries/block, 4 lanes/query, LDS-staged two-phase scan ------
constexpr int QPB = 64;
constexpr int NT2 = 256;                      // 4 waves
constexpr int MAIN_BLOCKS = ROWS / QPB;       // 512
constexpr int BPB = M / QPB;                  // 64 blocks per batch
constexpr int CH  = 1024;                     // chunk candidates (16 KB LDS)

__global__ __launch_bounds__(NT2) void pml_main(const int* __restrict__ cStart,
                                                const float4* __restrict__ cPk,
                                                const float4* __restrict__ qPk,
                                                float* __restrict__ out) {
    __shared__ float4 cs[CH + 8];
    __shared__ float sA[4], sB[4];

    const int t    = threadIdx.x;
    const int sub  = t & 3;
    const int ql   = t >> 2;                  // 0..63
    const int b    = blockIdx.x / BPB;
    const int qbase = (blockIdx.x % BPB) * QPB;
    const int lane = t & 63, wid = t >> 6;

    const float4 Q = qPk[(size_t)b * M + qbase + ql];
    const float px = -Q.x, py = -Q.y, pz = -Q.z, psq = Q.w;
    const int* bs = cStart + b * (NB + 1);
    const float4* cb = cPk + (size_t)b * N;

    // block x-extremes (within-bin order arbitrary -> reduce)
    float xmn = Q.x, xmx = Q.x;
#pragma unroll
    for (int o = 1; o < 64; o <<= 1) {
        xmn = fminf(xmn, __shfl_xor(xmn, o));
        xmx = fmaxf(xmx, __shfl_xor(xmx, o));
    }
    if (lane == 0) { sA[wid] = xmn; sB[wid] = xmx; }
    __syncthreads();
    const float xL = fminf(fminf(sA[0], sA[1]), fminf(sA[2], sA[3]));
    const float xR = fmaxf(fmaxf(sB[0], sB[1]), fmaxf(sB[2], sB[3]));

    const int l0 = max(binOf(xL) - 1, 0);
    const int r0 = min(binOf(xR) + 1, NB - 1);
    const int lo = bs[l0], hi = bs[r0 + 1];

    float fm = FMAX;

    // chunked staged scan: uniform trip counts (bounds block-uniform),
    // sentinel pad (f(sentinel) = FMAX) -> no tail divergence.
    auto scan_range = [&](int lo_, int hi_) {
        for (int base_ = lo_; base_ < hi_; base_ += CH) {
            const int cnt    = min(CH, hi_ - base_);
            const int cntPad = (cnt + 7) & ~7;
            __syncthreads();                              // cs reuse (WAR)
            for (int i = t; i < cnt; i += NT2) cs[i] = cb[base_ + i];
            if (t < cntPad - cnt) cs[cnt + t] = make_float4(0.f, 0.f, 0.f, FMAX);
            __syncthreads();
#pragma unroll 2
            for (int k = sub; k < cntPad; k += 8) {       // lane: k, k+4
                float4 c0 = cs[k];
                float4 c1 = cs[k + 4];
                float f0 = fmaf(px, c0.x, fmaf(py, c0.y, fmaf(pz, c0.z, c0.w)));
                float f1 = fmaf(px, c1.x, fmaf(py, c1.y, fmaf(pz, c1.z, c1.w)));
                fm = fminf(fm, fminf(f0, f1));            // v_min3_f32
            }
        }
    };

    scan_range(lo, hi);                                   // phase 1

    // per-query d_ub^2 -> block max -> md
    float bq = fminf(fm, __shfl_xor(fm, 1));
    bq = fminf(bq, __shfl_xor(bq, 2));
    float mx = fmaxf(fmaf(2.0f, bq, psq), 0.0f);
#pragma unroll
    for (int o = 1; o < 64; o <<= 1) mx = fmaxf(mx, __shfl_xor(mx, o));
    __syncthreads();
    if (lane == 0) sA[wid] = mx;
    __syncthreads();
    const float md = sqrtf(fmaxf(fmaxf(sA[0], sA[1]), fmaxf(sA[2], sA[3])));

    const int lT = binOf(xL - md);                        // saturating cvt: inf-safe
    const int rT = binOf(xR + md);
    const int lo2 = bs[lT], hi2 = bs[rT + 1];

    scan_range(lo2, lo);                                  // phase 2 left delta
    scan_range(hi, hi2);                                  // phase 2 right delta

    // merge 4 lanes -> per-query distance; block sum
    bq = fminf(fm, __shfl_xor(fm, 1));
    bq = fminf(bq, __shfl_xor(bq, 2));
    float s = (sub == 0) ? sqrtf(fmaxf(fmaf(2.0f, bq, psq), 0.0f)) : 0.0f;
#pragma unroll
    for (int off = 32; off > 0; off >>= 1) s += __shfl_down(s, off);
    __syncthreads();
    if (lane == 0) sA[wid] = s;
    __syncthreads();
    if (t == 0)
        atomicAdd(out, (sA[0] + sA[1] + sA[2] + sA[3]) * (1.0f / (float)ROWS));
}

extern "C" void kernel_launch(void* const* d_in, const int* in_sizes, int n_in,
                              void* d_out, int out_size, void* d_ws, size_t ws_size,
                              hipStream_t stream) {
    const float* completed = (const float*)d_in[0];  // (8, 8192, 3)
    const float* partial   = (const float*)d_in[1];  // (8, 4096, 3)
    float* out = (float*)d_out;
    char*  ws  = (char*)d_ws;

    int*    cStart = (int*)ws;
    float4* cPk    = (float4*)(ws + OFF_CPK);
    float4* qPk    = (float4*)(ws + OFF_QPK);

    pml_prep<<<64, PT, 0, stream>>>(completed, partial, cStart, cPk, qPk, out);
    pml_main<<<MAIN_BLOCKS, NT2, 0, stream>>>(cStart, cPk, qPk, out);
}